// Round 1
// baseline (2799.006 us; speedup 1.0000x reference)
//
#include <hip/hip_runtime.h>
#include <stdint.h>

// AmbientSphericalBrownianMotion: 100 Stratonovich-Heun steps of spherical BM.
// RNG = modern JAX (jax_threefry_partitionable=True): bits[j] = w0^w1 of
// threefry2x32(step_key, (0,j)); step_key = fold_in(key(1), i).
// VALU-issue-bound; threefry (~432 of ~613 slots/thread/step) is
// bit-exactness-locked 32-bit int -> cannot pack.
// Round-6 change: all FP32 math packed across the thread's two points (A,B)
// as float2 -> v_pk_fma_f32/v_pk_add_f32/v_pk_mul_f32 (full-rate on CDNA):
//  - 3 packed erfinv chains instead of 6 scalar (Horner 54->27 slots)
//  - 1 packed Heun step instead of 2 scalar (~48->~26 slots)
//  - identical op order per half -> bit-identical results to round-5
//  - LDS step-key prefetched one iteration ahead (lgkm wait off hot path)

#define BLOCK 256

typedef float v2f __attribute__((ext_vector_type(2)));

__device__ __forceinline__ v2f pk_fma(v2f a, v2f b, v2f c) {
    return __builtin_elementwise_fma(a, b, c);
}
__device__ __forceinline__ v2f sp(float f) { return v2f{f, f}; }

__device__ __forceinline__ void tf_round(uint32_t& x0, uint32_t& x1, int r) {
    x0 += x1;
    x1 = (x1 << r) | (x1 >> (32 - r));   // -> v_alignbit_b32
    x1 ^= x0;
}

// JAX / Random123 Threefry-2x32, 20 rounds. k0,k1 wave-uniform (SGPR) in the
// hot loop -> key schedule on SALU, keys fold in as SGPR operands.
__device__ __forceinline__ uint2 threefry2x32(uint32_t k0, uint32_t k1,
                                              uint32_t x0, uint32_t x1) {
    uint32_t k2 = k0 ^ k1 ^ 0x1BD11BDAu;
    x0 += k0; x1 += k1;
    tf_round(x0,x1,13); tf_round(x0,x1,15); tf_round(x0,x1,26); tf_round(x0,x1,6);
    x0 += k1; x1 += k2 + 1u;
    tf_round(x0,x1,17); tf_round(x0,x1,29); tf_round(x0,x1,16); tf_round(x0,x1,24);
    x0 += k2; x1 += k0 + 2u;
    tf_round(x0,x1,13); tf_round(x0,x1,15); tf_round(x0,x1,26); tf_round(x0,x1,6);
    x0 += k0; x1 += k1 + 3u;
    tf_round(x0,x1,17); tf_round(x0,x1,29); tf_round(x0,x1,16); tf_round(x0,x1,24);
    x0 += k1; x1 += k2 + 4u;
    tf_round(x0,x1,13); tf_round(x0,x1,15); tf_round(x0,x1,26); tf_round(x0,x1,6);
    x0 += k2; x1 += k0 + 5u;
    return make_uint2(x0, x1);
}

// Partitionable random_bits (32-bit): xor of both output words, counter (0, j).
__device__ __forceinline__ uint32_t tf_bits(uint32_t k0, uint32_t k1, uint32_t j) {
    uint2 h = threefry2x32(k0, k1, 0u, j);
    return h.x ^ h.y;
}

struct Coef { float a[9]; };

// (bitsA, bitsB) -> packed increment (incA, incB) = sqrt(2)*erfinv(u)*sdt.
// Scale c prefolded into the primary Horner coefficients (C.a[i] = c*orig[i]).
// Tail: w>=5 <=> tt <= e^-5; per-pair __any branch (~35%/iter taken), packed.
// Per-half op order identical to the round-5 scalar version -> bit-identical.
__device__ __forceinline__ v2f bits2_to_inc(uint32_t ba, uint32_t bb,
                                            const Coef& C, float cc) {
    const float mn   = -0.99999994f;                                // 0xBF7FFFFF
    const float eTm5 =  6.7379470e-3f;                              // e^-5
    const float nln2 = -0.69314718f;
    v2f f = { __uint_as_float((ba >> 9) | 0x3f800000u),
              __uint_as_float((bb >> 9) | 0x3f800000u) };
    v2f u01 = f - sp(1.0f);               // [0,1), exact (f in [1,2))
    v2f u   = pk_fma(u01, sp(2.0f), sp(mn));   // >= mn always
    v2f s   = u * u;
    v2f tt  = sp(1.0f) - s;               // Sterbenz-exact in tail
    v2f lg  = { __log2f(tt.x), __log2f(tt.y) };   // scalar trans x2
    v2f wa  = pk_fma(lg, sp(nln2), sp(-2.5f));    // w - 2.5
    v2f p = sp(C.a[0]);
    p = pk_fma(p, wa, sp(C.a[1]));
    p = pk_fma(p, wa, sp(C.a[2]));
    p = pk_fma(p, wa, sp(C.a[3]));
    p = pk_fma(p, wa, sp(C.a[4]));
    p = pk_fma(p, wa, sp(C.a[5]));
    p = pk_fma(p, wa, sp(C.a[6]));
    p = pk_fma(p, wa, sp(C.a[7]));
    p = pk_fma(p, wa, sp(C.a[8]));        // == c * poly_a(wa)
    if (__builtin_expect(__any((tt.x <= eTm5) || (tt.y <= eTm5)), 0)) {
        v2f w  = lg * sp(nln2);
        v2f sq = { __builtin_amdgcn_sqrtf(w.x), __builtin_amdgcn_sqrtf(w.y) };
        v2f wb = sq - sp(3.0f);
        v2f q = sp(-0.000200214257f);
        q = pk_fma(q, wb, sp( 0.000100950558f));
        q = pk_fma(q, wb, sp( 0.00134934322f));
        q = pk_fma(q, wb, sp(-0.00367342844f));
        q = pk_fma(q, wb, sp( 0.00573950773f));
        q = pk_fma(q, wb, sp(-0.0076224613f));
        q = pk_fma(q, wb, sp( 0.00943887047f));
        q = pk_fma(q, wb, sp( 1.00167406f));
        q = pk_fma(q, wb, sp( 2.83297682f));
        q = q * sp(cc);
        p.x = (tt.x > eTm5) ? p.x : q.x;
        p.y = (tt.y > eTm5) ? p.y : q.y;
    }
    return p * u;
}

__device__ __forceinline__ v2f rcp2(v2f a) {
    return v2f{ __builtin_amdgcn_rcpf(a.x), __builtin_amdgcn_rcpf(a.y) };
}
__device__ __forceinline__ v2f rsq2(v2f a) {
    return v2f{ __builtin_amdgcn_rsqf(a.x), __builtin_amdgcn_rsqf(a.y) };
}

// Packed state: component c of points (A, B) lives in one v2f.
struct P2 { v2f x, y, z; };

// |p| == 1 on entry (renormalized every step). Round-5 algebra, packed:
//   yp = p + inc - d*p = pi - d*p        (pi = p + inc)
//   2*y1 = pi + (1-q2)*yp; normalize kills the factor 2 exactly.
__device__ __forceinline__ void heun2(P2& p, v2f ix, v2f iy, v2f iz) {
    v2f d   = pk_fma(p.z, iz, pk_fma(p.y, iy, p.x * ix));
    v2f pix = p.x + ix, piy = p.y + iy, piz = p.z + iz;
    v2f nd  = -d;
    v2f ypx = pk_fma(nd, p.x, pix);
    v2f ypy = pk_fma(nd, p.y, piy);
    v2f ypz = pk_fma(nd, p.z, piz);
    v2f d2  = pk_fma(ypz, iz, pk_fma(ypy, iy, ypx * ix));
    v2f m2  = pk_fma(ypz, ypz, pk_fma(ypy, ypy, ypx * ypx));
    v2f q2  = d2 * rcp2(m2);
    v2f t   = sp(1.0f) - q2;
    v2f yhx = pk_fma(t, ypx, pix);        // = 2*y1
    v2f yhy = pk_fma(t, ypy, piy);
    v2f yhz = pk_fma(t, ypz, piz);
    v2f r2  = pk_fma(yhz, yhz, pk_fma(yhy, yhy, yhx * yhx));
    v2f ri  = rsq2(r2);
    p.x = yhx * ri; p.y = yhy * ri; p.z = yhz * ri;
}

__global__ __launch_bounds__(BLOCK)
void sbm_kernel(const float* __restrict__ xin,
                const int* __restrict__ t_ptr,
                const int* __restrict__ steps_ptr,
                float* __restrict__ out,
                uint32_t nhalf) {
    __shared__ uint2 skeys[128];

    const int steps = steps_ptr[0];
    const int tval  = t_ptr[0];
    const int tid   = threadIdx.x;

    // Per-step keys: fold_in(key(1), i) = threefry2x32((0,1), (0,i)).
    if (tid < steps && tid < 128) skeys[tid] = threefry2x32(0u, 1u, 0u, (uint32_t)tid);
    __syncthreads();

    const float dt  = (float)((double)tval / (double)steps);  // f32(t/steps)
    const float sdt = sqrtf(dt);
    const float c   = 1.41421356237f * sdt;   // sqrt2 * sdt

    // c-scaled primary-branch Horner coefficients (exactly c*poly by induction)
    Coef C;
    C.a[0] = c *  2.81022636e-08f;
    C.a[1] = c *  3.43273939e-07f;
    C.a[2] = c * -3.5233877e-06f;
    C.a[3] = c * -4.39150654e-06f;
    C.a[4] = c *  0.00021858087f;
    C.a[5] = c * -0.00125372503f;
    C.a[6] = c * -0.00417768164f;
    C.a[7] = c *  0.246640727f;
    C.a[8] = c *  1.50140941f;

    const uint32_t g = blockIdx.x * BLOCK + tid;
    if (g >= nhalf) return;

    const float* pa = xin + 3u * g;
    const float* pb = xin + 3u * (g + nhalf);
    P2 P;
    P.x = v2f{ pa[0], pb[0] };
    P.y = v2f{ pa[1], pb[1] };
    P.z = v2f{ pa[2], pb[2] };
    const uint32_t ja = 3u * g;
    const uint32_t jb = 3u * (g + nhalf);

    uint2 key = skeys[0];
    for (int i = 0; i < steps; ++i) {
        uint32_t k0 = __builtin_amdgcn_readfirstlane(key.x);
        uint32_t k1 = __builtin_amdgcn_readfirstlane(key.y);
        uint2 keyn = skeys[(i + 1) & 127];   // prefetch next step key (unused
                                             // garbage on last iter is fine)
        uint32_t a0 = tf_bits(k0, k1, ja);
        uint32_t a1 = tf_bits(k0, k1, ja + 1u);
        uint32_t a2 = tf_bits(k0, k1, ja + 2u);
        uint32_t b0 = tf_bits(k0, k1, jb);
        uint32_t b1 = tf_bits(k0, k1, jb + 1u);
        uint32_t b2 = tf_bits(k0, k1, jb + 2u);
        v2f i0 = bits2_to_inc(a0, b0, C, c);
        v2f i1 = bits2_to_inc(a1, b1, C, c);
        v2f i2 = bits2_to_inc(a2, b2, C, c);
        heun2(P, i0, i1, i2);
        key = keyn;
    }

    float* oa = out + 3u * g;
    float* ob = out + 3u * (g + nhalf);
    oa[0] = P.x.x; oa[1] = P.y.x; oa[2] = P.z.x;
    ob[0] = P.x.y; ob[1] = P.y.y; ob[2] = P.z.y;
}

extern "C" void kernel_launch(void* const* d_in, const int* in_sizes, int n_in,
                              void* d_out, int out_size, void* d_ws, size_t ws_size,
                              hipStream_t stream) {
    const float* x      = (const float*)d_in[0];
    const int*   t_ptr  = (const int*)d_in[1];
    const int*   steps  = (const int*)d_in[2];
    float*       out    = (float*)d_out;

    const uint32_t npts  = (uint32_t)(in_sizes[0] / 3);    // 4194304 points
    const uint32_t nhalf = npts / 2;                       // 2097152 threads
    const uint32_t grid  = (nhalf + BLOCK - 1) / BLOCK;    // 8192 blocks

    sbm_kernel<<<grid, BLOCK, 0, stream>>>(x, t_ptr, steps, out, nhalf);
}

// Round 2
// 2748.289 us; speedup vs baseline: 1.0185x; 1.0185x over previous
//
#include <hip/hip_runtime.h>
#include <stdint.h>

// AmbientSphericalBrownianMotion: 100 Stratonovich-Heun steps of spherical BM.
// RNG = modern JAX (jax_threefry_partitionable=True): bits[j] = w0^w1 of
// threefry2x32(step_key, (0,j)); step_key = fold_in(key(1), i).
// VALU-issue-bound; threefry (~438 of ~610 slots/point-pair/step) is
// bit-exactness-locked 32-bit int.
// Round-7: REVERT round-6 packed-f32 (v_pk_fma_f32 is half-rate on CDNA4 ->
// regression). Back to round-5 scalar math (bit-identical), plus:
//  - 4 points/thread (A,B,C,D as two pairs): halves per-step fixed cost
//    (LDS key read, readfirstlane x2, loop bookkeeping) per sample, more ILP
//  - step key prefetched one iteration ahead (lgkm wait off dependent path)

#define BLOCK 256

struct V3 { float x, y, z; };

__device__ __forceinline__ void tf_round(uint32_t& x0, uint32_t& x1, int r) {
    x0 += x1;
    x1 = (x1 << r) | (x1 >> (32 - r));   // -> v_alignbit_b32
    x1 ^= x0;
}

// JAX / Random123 Threefry-2x32, 20 rounds. k0,k1 wave-uniform (SGPR) in the
// hot loop -> key schedule on SALU, keys fold in as SGPR operands.
__device__ __forceinline__ uint2 threefry2x32(uint32_t k0, uint32_t k1,
                                              uint32_t x0, uint32_t x1) {
    uint32_t k2 = k0 ^ k1 ^ 0x1BD11BDAu;
    x0 += k0; x1 += k1;
    tf_round(x0,x1,13); tf_round(x0,x1,15); tf_round(x0,x1,26); tf_round(x0,x1,6);
    x0 += k1; x1 += k2 + 1u;
    tf_round(x0,x1,17); tf_round(x0,x1,29); tf_round(x0,x1,16); tf_round(x0,x1,24);
    x0 += k2; x1 += k0 + 2u;
    tf_round(x0,x1,13); tf_round(x0,x1,15); tf_round(x0,x1,26); tf_round(x0,x1,6);
    x0 += k0; x1 += k1 + 3u;
    tf_round(x0,x1,17); tf_round(x0,x1,29); tf_round(x0,x1,16); tf_round(x0,x1,24);
    x0 += k1; x1 += k2 + 4u;
    tf_round(x0,x1,13); tf_round(x0,x1,15); tf_round(x0,x1,26); tf_round(x0,x1,6);
    x0 += k2; x1 += k0 + 5u;
    return make_uint2(x0, x1);
}

// Partitionable random_bits (32-bit): xor of both output words, counter (0, j).
__device__ __forceinline__ uint32_t tf_bits(uint32_t k0, uint32_t k1, uint32_t j) {
    uint2 h = threefry2x32(k0, k1, 0u, j);
    return h.x ^ h.y;
}

struct Coef { float a[9]; };

// bits -> increment = sqrt(2)*erfinv(u)*sdt; the scale c is prefolded into
// the primary Horner coefficients (C.a[i] = c * orig[i], giving exactly c*p).
// Tail: w>=5 <=> tt <= e^-5; 0.34%/sample, wave-uniform branch (~20%/wave).
__device__ __forceinline__ float bits_to_inc(uint32_t bits, const Coef& C, float c) {
    const float mn   = -0.99999994f;                                // 0xBF7FFFFF
    const float eTm5 =  6.7379470e-3f;                              // e^-5
    float u01 = __uint_as_float((bits >> 9) | 0x3f800000u) - 1.0f;  // [0,1)
    float u   = fmaf(u01, 2.0f, mn);      // >= mn always; fmax provably redundant
    float s   = u * u;
    float tt  = 1.0f - s;                 // Sterbenz-exact in tail
    float lg  = __log2f(tt);              // v_log_f32
    const float nln2 = -0.69314718f;
    float wa  = fmaf(lg, nln2, -2.5f);    // w - 2.5
    float p = C.a[0];
    p = fmaf(p, wa, C.a[1]);
    p = fmaf(p, wa, C.a[2]);
    p = fmaf(p, wa, C.a[3]);
    p = fmaf(p, wa, C.a[4]);
    p = fmaf(p, wa, C.a[5]);
    p = fmaf(p, wa, C.a[6]);
    p = fmaf(p, wa, C.a[7]);
    p = fmaf(p, wa, C.a[8]);              // == c * poly_a(wa)
    if (__builtin_expect(__any(tt <= eTm5), 0)) {
        float w  = lg * nln2;
        float wb = __builtin_amdgcn_sqrtf(w) - 3.0f;
        float q = -0.000200214257f;
        q = fmaf(q, wb,  0.000100950558f);
        q = fmaf(q, wb,  0.00134934322f);
        q = fmaf(q, wb, -0.00367342844f);
        q = fmaf(q, wb,  0.00573950773f);
        q = fmaf(q, wb, -0.0076224613f);
        q = fmaf(q, wb,  0.00943887047f);
        q = fmaf(q, wb,  1.00167406f);
        q = fmaf(q, wb,  2.83297682f);
        q = q * c;
        p = (tt > eTm5) ? p : q;
    }
    return p * u;
}

__device__ __forceinline__ float rcp_f(float a) { return __builtin_amdgcn_rcpf(a); }

// |p| == 1 on entry (renormalized every step). Algebra:
//   yp = p + inc - d*p = pi - d*p        (pi = p + inc)
//   2*y1 = p + inc + (1-q2)*yp = pi + t*yp
//   normalize kills the factor 2 exactly.
__device__ __forceinline__ void heun_step(V3& p, V3 inc) {
    float d  = p.x*inc.x + p.y*inc.y + p.z*inc.z;
    V3 pi = { p.x + inc.x, p.y + inc.y, p.z + inc.z };
    V3 yp = { pi.x - d*p.x, pi.y - d*p.y, pi.z - d*p.z };
    float d2 = yp.x*inc.x + yp.y*inc.y + yp.z*inc.z;
    float m2 = yp.x*yp.x + yp.y*yp.y + yp.z*yp.z;
    float q2 = d2 * rcp_f(m2);
    float t  = 1.0f - q2;
    V3 yh = { pi.x + t*yp.x, pi.y + t*yp.y, pi.z + t*yp.z };   // = 2*y1
    float r2   = yh.x*yh.x + yh.y*yh.y + yh.z*yh.z;
    float rinv = __builtin_amdgcn_rsqf(r2);
    p.x = yh.x * rinv; p.y = yh.y * rinv; p.z = yh.z * rinv;
}

__global__ __launch_bounds__(BLOCK)
void sbm_kernel(const float* __restrict__ xin,
                const int* __restrict__ t_ptr,
                const int* __restrict__ steps_ptr,
                float* __restrict__ out,
                uint32_t nq) {
    __shared__ uint2 skeys[128];

    const int steps = steps_ptr[0];
    const int tval  = t_ptr[0];
    const int tid   = threadIdx.x;

    // Per-step keys: fold_in(key(1), i) = threefry2x32((0,1), (0,i)).
    if (tid < steps && tid < 128) skeys[tid] = threefry2x32(0u, 1u, 0u, (uint32_t)tid);
    __syncthreads();

    const float dt  = (float)((double)tval / (double)steps);  // f32(t/steps)
    const float sdt = sqrtf(dt);
    const float c   = 1.41421356237f * sdt;   // sqrt2 * sdt

    // c-scaled primary-branch Horner coefficients (exactly c*poly by induction)
    Coef C;
    C.a[0] = c *  2.81022636e-08f;
    C.a[1] = c *  3.43273939e-07f;
    C.a[2] = c * -3.5233877e-06f;
    C.a[3] = c * -4.39150654e-06f;
    C.a[4] = c *  0.00021858087f;
    C.a[5] = c * -0.00125372503f;
    C.a[6] = c * -0.00417768164f;
    C.a[7] = c *  0.246640727f;
    C.a[8] = c *  1.50140941f;

    const uint32_t g = blockIdx.x * BLOCK + tid;
    if (g >= nq) return;

    // 4 points: g, g+nq, g+2nq, g+3nq. Flat RNG counter for point p is 3p.
    const float* pa = xin + 3u * g;
    const float* pb = xin + 3u * (g + nq);
    const float* pc = xin + 3u * (g + 2u * nq);
    const float* pd = xin + 3u * (g + 3u * nq);
    V3 A = { pa[0], pa[1], pa[2] };
    V3 B = { pb[0], pb[1], pb[2] };
    V3 Cc = { pc[0], pc[1], pc[2] };
    V3 Dd = { pd[0], pd[1], pd[2] };
    const uint32_t ja = 3u * g;
    const uint32_t jb = 3u * (g + nq);
    const uint32_t jc = 3u * (g + 2u * nq);
    const uint32_t jd = 3u * (g + 3u * nq);

    uint2 key = skeys[0];
    for (int i = 0; i < steps; ++i) {
        uint32_t k0 = __builtin_amdgcn_readfirstlane(key.x);
        uint32_t k1 = __builtin_amdgcn_readfirstlane(key.y);
        uint2 keyn = skeys[(i + 1) & 127];   // prefetch next step key (unused
                                             // garbage on last iter is fine)
        // pair 1: A, B
        {
            uint32_t a0 = tf_bits(k0, k1, ja);
            uint32_t a1 = tf_bits(k0, k1, ja + 1u);
            uint32_t a2 = tf_bits(k0, k1, ja + 2u);
            uint32_t b0 = tf_bits(k0, k1, jb);
            uint32_t b1 = tf_bits(k0, k1, jb + 1u);
            uint32_t b2 = tf_bits(k0, k1, jb + 2u);
            V3 incA = { bits_to_inc(a0, C, c), bits_to_inc(a1, C, c), bits_to_inc(a2, C, c) };
            V3 incB = { bits_to_inc(b0, C, c), bits_to_inc(b1, C, c), bits_to_inc(b2, C, c) };
            heun_step(A, incA);
            heun_step(B, incB);
        }
        // pair 2: C, D
        {
            uint32_t c0 = tf_bits(k0, k1, jc);
            uint32_t c1 = tf_bits(k0, k1, jc + 1u);
            uint32_t c2 = tf_bits(k0, k1, jc + 2u);
            uint32_t d0 = tf_bits(k0, k1, jd);
            uint32_t d1 = tf_bits(k0, k1, jd + 1u);
            uint32_t d2 = tf_bits(k0, k1, jd + 2u);
            V3 incC = { bits_to_inc(c0, C, c), bits_to_inc(c1, C, c), bits_to_inc(c2, C, c) };
            V3 incD = { bits_to_inc(d0, C, c), bits_to_inc(d1, C, c), bits_to_inc(d2, C, c) };
            heun_step(Cc, incC);
            heun_step(Dd, incD);
        }
        key = keyn;
    }

    float* oa = out + 3u * g;
    float* ob = out + 3u * (g + nq);
    float* oc = out + 3u * (g + 2u * nq);
    float* od = out + 3u * (g + 3u * nq);
    oa[0] = A.x;  oa[1] = A.y;  oa[2] = A.z;
    ob[0] = B.x;  ob[1] = B.y;  ob[2] = B.z;
    oc[0] = Cc.x; oc[1] = Cc.y; oc[2] = Cc.z;
    od[0] = Dd.x; od[1] = Dd.y; od[2] = Dd.z;
}

extern "C" void kernel_launch(void* const* d_in, const int* in_sizes, int n_in,
                              void* d_out, int out_size, void* d_ws, size_t ws_size,
                              hipStream_t stream) {
    const float* x      = (const float*)d_in[0];
    const int*   t_ptr  = (const int*)d_in[1];
    const int*   steps  = (const int*)d_in[2];
    float*       out    = (float*)d_out;

    const uint32_t npts = (uint32_t)(in_sizes[0] / 3);     // 4194304 points
    const uint32_t nq   = npts / 4;                        // 1048576 threads
    const uint32_t grid = (nq + BLOCK - 1) / BLOCK;        // 4096 blocks

    sbm_kernel<<<grid, BLOCK, 0, stream>>>(x, t_ptr, steps, out, nq);
}

// Round 3
// 2612.684 us; speedup vs baseline: 1.0713x; 1.0519x over previous
//
#include <hip/hip_runtime.h>
#include <stdint.h>

// AmbientSphericalBrownianMotion: 100 Stratonovich-Heun steps of spherical BM.
// RNG = modern JAX (jax_threefry_partitionable=True): bits[j] = w0^w1 of
// threefry2x32(step_key, (0,j)); step_key = fold_in(key(1), i).
// VALU-issue-bound; threefry (~432 of ~620 slots/thread/step) is
// bit-exactness-locked 32-bit int.
// Round-8: revert to round-5 structure (2 pts/thread, VGPR-24 profile) after
// r6 (packed f32 = half-rate on CDNA4, -6%) and r7 (4 pts/thread, occupancy
// 86->68%, -4%) both regressed. Micro-shaves only, all bit-identical:
//  - v_alignbit_b32 builds (bits>>9)|0x3f800000 in 1 op (was lshr+or)
//  - tail predicate computed once (CSE for __any + select)
//  - step key prefetched one iteration ahead (lgkm wait off dependent path)

#define BLOCK 256

struct V3 { float x, y, z; };

__device__ __forceinline__ void tf_round(uint32_t& x0, uint32_t& x1, int r) {
    x0 += x1;
    x1 = (x1 << r) | (x1 >> (32 - r));   // -> v_alignbit_b32
    x1 ^= x0;
}

// JAX / Random123 Threefry-2x32, 20 rounds. k0,k1 wave-uniform (SGPR) in the
// hot loop -> key schedule on SALU, keys fold in as SGPR operands.
__device__ __forceinline__ uint2 threefry2x32(uint32_t k0, uint32_t k1,
                                              uint32_t x0, uint32_t x1) {
    uint32_t k2 = k0 ^ k1 ^ 0x1BD11BDAu;
    x0 += k0; x1 += k1;
    tf_round(x0,x1,13); tf_round(x0,x1,15); tf_round(x0,x1,26); tf_round(x0,x1,6);
    x0 += k1; x1 += k2 + 1u;
    tf_round(x0,x1,17); tf_round(x0,x1,29); tf_round(x0,x1,16); tf_round(x0,x1,24);
    x0 += k2; x1 += k0 + 2u;
    tf_round(x0,x1,13); tf_round(x0,x1,15); tf_round(x0,x1,26); tf_round(x0,x1,6);
    x0 += k0; x1 += k1 + 3u;
    tf_round(x0,x1,17); tf_round(x0,x1,29); tf_round(x0,x1,16); tf_round(x0,x1,24);
    x0 += k1; x1 += k2 + 4u;
    tf_round(x0,x1,13); tf_round(x0,x1,15); tf_round(x0,x1,26); tf_round(x0,x1,6);
    x0 += k2; x1 += k0 + 5u;
    return make_uint2(x0, x1);
}

// Partitionable random_bits (32-bit): xor of both output words, counter (0, j).
__device__ __forceinline__ uint32_t tf_bits(uint32_t k0, uint32_t k1, uint32_t j) {
    uint2 h = threefry2x32(k0, k1, 0u, j);
    return h.x ^ h.y;
}

struct Coef { float a[9]; };

// bits -> increment = sqrt(2)*erfinv(u)*sdt; the scale c is prefolded into
// the primary Horner coefficients (C.a[i] = c * orig[i], giving exactly c*p).
// Tail: w>=5 <=> tt <= e^-5; 0.34%/sample, ~20%/wave-call branch.
__device__ __forceinline__ float bits_to_inc(uint32_t bits, const Coef& C, float c) {
    const float mn   = -0.99999994f;                                // 0xBF7FFFFF
    const float eTm5 =  6.7379470e-3f;                              // e^-5
    // (bits>>9) | 0x3f800000 == alignbit(0x7F, bits, 9): one VALU op.
    float f   = __uint_as_float(__builtin_amdgcn_alignbit(0x7Fu, bits, 9u));
    float u01 = f - 1.0f;                 // [0,1), exact (f in [1,2))
    float u   = fmaf(u01, 2.0f, mn);      // >= mn always; fmax provably redundant
    float s   = u * u;
    float tt  = 1.0f - s;                 // Sterbenz-exact in tail
    float lg  = __log2f(tt);              // v_log_f32
    const float nln2 = -0.69314718f;
    float wa  = fmaf(lg, nln2, -2.5f);    // w - 2.5
    float p = C.a[0];
    p = fmaf(p, wa, C.a[1]);
    p = fmaf(p, wa, C.a[2]);
    p = fmaf(p, wa, C.a[3]);
    p = fmaf(p, wa, C.a[4]);
    p = fmaf(p, wa, C.a[5]);
    p = fmaf(p, wa, C.a[6]);
    p = fmaf(p, wa, C.a[7]);
    p = fmaf(p, wa, C.a[8]);              // == c * poly_a(wa)
    bool tl = tt <= eTm5;                 // one v_cmp, reused by __any + select
    if (__builtin_expect(__any(tl), 0)) {
        float w  = lg * nln2;
        float wb = __builtin_amdgcn_sqrtf(w) - 3.0f;
        float q = -0.000200214257f;
        q = fmaf(q, wb,  0.000100950558f);
        q = fmaf(q, wb,  0.00134934322f);
        q = fmaf(q, wb, -0.00367342844f);
        q = fmaf(q, wb,  0.00573950773f);
        q = fmaf(q, wb, -0.0076224613f);
        q = fmaf(q, wb,  0.00943887047f);
        q = fmaf(q, wb,  1.00167406f);
        q = fmaf(q, wb,  2.83297682f);
        q = q * c;
        p = tl ? q : p;
    }
    return p * u;
}

__device__ __forceinline__ float rcp_f(float a) { return __builtin_amdgcn_rcpf(a); }

// |p| == 1 on entry (renormalized every step). Algebra:
//   yp = p + inc - d*p = pi - d*p        (pi = p + inc)
//   2*y1 = p + inc + (1-q2)*yp = pi + t*yp
//   normalize kills the factor 2 exactly.
__device__ __forceinline__ void heun_step(V3& p, V3 inc) {
    float d  = p.x*inc.x + p.y*inc.y + p.z*inc.z;
    V3 pi = { p.x + inc.x, p.y + inc.y, p.z + inc.z };
    V3 yp = { pi.x - d*p.x, pi.y - d*p.y, pi.z - d*p.z };
    float d2 = yp.x*inc.x + yp.y*inc.y + yp.z*inc.z;
    float m2 = yp.x*yp.x + yp.y*yp.y + yp.z*yp.z;
    float q2 = d2 * rcp_f(m2);
    float t  = 1.0f - q2;
    V3 yh = { pi.x + t*yp.x, pi.y + t*yp.y, pi.z + t*yp.z };   // = 2*y1
    float r2   = yh.x*yh.x + yh.y*yh.y + yh.z*yh.z;
    float rinv = __builtin_amdgcn_rsqf(r2);
    p.x = yh.x * rinv; p.y = yh.y * rinv; p.z = yh.z * rinv;
}

__global__ __launch_bounds__(BLOCK)
void sbm_kernel(const float* __restrict__ xin,
                const int* __restrict__ t_ptr,
                const int* __restrict__ steps_ptr,
                float* __restrict__ out,
                uint32_t nhalf) {
    __shared__ uint2 skeys[128];

    const int steps = steps_ptr[0];
    const int tval  = t_ptr[0];
    const int tid   = threadIdx.x;

    // Per-step keys: fold_in(key(1), i) = threefry2x32((0,1), (0,i)).
    if (tid < steps && tid < 128) skeys[tid] = threefry2x32(0u, 1u, 0u, (uint32_t)tid);
    __syncthreads();

    const float dt  = (float)((double)tval / (double)steps);  // f32(t/steps)
    const float sdt = sqrtf(dt);
    const float c   = 1.41421356237f * sdt;   // sqrt2 * sdt

    // c-scaled primary-branch Horner coefficients (exactly c*poly by induction)
    Coef C;
    C.a[0] = c *  2.81022636e-08f;
    C.a[1] = c *  3.43273939e-07f;
    C.a[2] = c * -3.5233877e-06f;
    C.a[3] = c * -4.39150654e-06f;
    C.a[4] = c *  0.00021858087f;
    C.a[5] = c * -0.00125372503f;
    C.a[6] = c * -0.00417768164f;
    C.a[7] = c *  0.246640727f;
    C.a[8] = c *  1.50140941f;

    const uint32_t g = blockIdx.x * BLOCK + tid;
    if (g >= nhalf) return;

    const float* pa = xin + 3u * g;
    const float* pb = xin + 3u * (g + nhalf);
    V3 A = { pa[0], pa[1], pa[2] };
    V3 B = { pb[0], pb[1], pb[2] };
    const uint32_t ja = 3u * g;
    const uint32_t jb = 3u * (g + nhalf);

    uint2 key = skeys[0];
    for (int i = 0; i < steps; ++i) {
        uint32_t k0 = __builtin_amdgcn_readfirstlane(key.x);
        uint32_t k1 = __builtin_amdgcn_readfirstlane(key.y);
        uint2 keyn = skeys[(i + 1) & 127];   // prefetch next step key (unused
                                             // garbage on last iter is fine)
        uint32_t a0 = tf_bits(k0, k1, ja);
        uint32_t a1 = tf_bits(k0, k1, ja + 1u);
        uint32_t a2 = tf_bits(k0, k1, ja + 2u);
        uint32_t b0 = tf_bits(k0, k1, jb);
        uint32_t b1 = tf_bits(k0, k1, jb + 1u);
        uint32_t b2 = tf_bits(k0, k1, jb + 2u);
        V3 incA = { bits_to_inc(a0, C, c), bits_to_inc(a1, C, c), bits_to_inc(a2, C, c) };
        V3 incB = { bits_to_inc(b0, C, c), bits_to_inc(b1, C, c), bits_to_inc(b2, C, c) };
        heun_step(A, incA);
        heun_step(B, incB);
        key = keyn;
    }

    float* oa = out + 3u * g;
    float* ob = out + 3u * (g + nhalf);
    oa[0] = A.x; oa[1] = A.y; oa[2] = A.z;
    ob[0] = B.x; ob[1] = B.y; ob[2] = B.z;
}

extern "C" void kernel_launch(void* const* d_in, const int* in_sizes, int n_in,
                              void* d_out, int out_size, void* d_ws, size_t ws_size,
                              hipStream_t stream) {
    const float* x      = (const float*)d_in[0];
    const int*   t_ptr  = (const int*)d_in[1];
    const int*   steps  = (const int*)d_in[2];
    float*       out    = (float*)d_out;

    const uint32_t npts  = (uint32_t)(in_sizes[0] / 3);    // 4194304 points
    const uint32_t nhalf = npts / 2;                       // 2097152 threads
    const uint32_t grid  = (nhalf + BLOCK - 1) / BLOCK;    // 8192 blocks

    sbm_kernel<<<grid, BLOCK, 0, stream>>>(x, t_ptr, steps, out, nhalf);
}